// Round 1
// baseline (538.426 us; speedup 1.0000x reference)
//
#include <hip/hip_runtime.h>
#include <math.h>

#define N_NODES 100000
#define D_IN 256
#define H1 16
#define H2 32
#define ROWS 32   // rows per block in the x@W1 kernel

// ---------- bf16 helpers (manual, RNE; avoids header surprises) ----------
static __device__ __forceinline__ float bf_lo(unsigned int u) {
    return __uint_as_float(u << 16);
}
static __device__ __forceinline__ float bf_hi(unsigned int u) {
    return __uint_as_float(u & 0xffff0000u);
}
static __device__ __forceinline__ unsigned int f2bf_rne(float f) {
    unsigned int u = __float_as_uint(f);
    return (u + 0x7fffu + ((u >> 16) & 1u)) >> 16;
}
static __device__ __forceinline__ unsigned int pack_bf16(float lo, float hi) {
    return f2bf_rne(lo) | (f2bf_rne(hi) << 16);
}

// ---------------- zero workspace region ----------------
__global__ void k_zero(float4* __restrict__ p, int n4) {
    int i = blockIdx.x * blockDim.x + threadIdx.x;
    if (i < n4) p[i] = make_float4(0.f, 0.f, 0.f, 0.f);
}

// ---------------- t = bf16(x @ W1)  [N,256]@[256,16] ----------------
// W1 staged TRANSPOSED in LDS so the k-loop runs on ds_read_b128:
// 3 b128 reads per 8 FMA (vs 3 b32 per 2 FMA before) -> 4x fewer LDS issues.
// Row stride D_IN+4 floats keeps the per-row base 16B-aligned and the
// 16 f-lanes of w1t 2-way-max on banks (free per m136).
__global__ __launch_bounds__(256) void k_xw1(const float* __restrict__ x,
                                             const float* __restrict__ W1,
                                             unsigned short* __restrict__ t,
                                             int n_nodes) {
    __shared__ float xs[ROWS][D_IN + 4];
    __shared__ float w1t[H1][D_IN + 4];
    const int tid = threadIdx.x;

    // stage W1 transposed: W1[k][f] -> w1t[f][k]  (4096 floats, once/block)
    for (int i = tid; i < D_IN * H1; i += 256) {
        int k = i >> 4, f = i & 15;
        w1t[f][k] = W1[i];
    }
    // load x tile: 32*256 floats = 2048 float4, coalesced
    const int row0 = blockIdx.x * ROWS;
    for (int i = tid; i < ROWS * D_IN / 4; i += 256) {
        int r  = i >> 6;          // 64 float4 per row
        int kc = i & 63;
        int grow = row0 + r;
        float4 v = (grow < n_nodes) ? ((const float4*)x)[grow * (D_IN / 4) + kc]
                                    : make_float4(0.f, 0.f, 0.f, 0.f);
        *(float4*)&xs[r][kc * 4] = v;
    }
    __syncthreads();

    const int f  = tid & 15;
    const int r0 = tid >> 4;      // rows r0 and r0+16
    float acc0 = 0.f, acc1 = 0.f;
#pragma unroll 8
    for (int k4 = 0; k4 < D_IN / 4; k4++) {
        float4 w = *(const float4*)&w1t[f][k4 * 4];       // 2-way bank, free
        float4 a = *(const float4*)&xs[r0][k4 * 4];       // broadcast per 16
        float4 b = *(const float4*)&xs[r0 + 16][k4 * 4];
        acc0 = fmaf(a.x, w.x, fmaf(a.y, w.y, fmaf(a.z, w.z, fmaf(a.w, w.w, acc0))));
        acc1 = fmaf(b.x, w.x, fmaf(b.y, w.y, fmaf(b.z, w.z, fmaf(b.w, w.w, acc1))));
    }
    int gr0 = row0 + r0, gr1 = row0 + r0 + 16;
    if (gr0 < n_nodes) t[gr0 * H1 + f] = (unsigned short)f2bf_rne(acc0);
    if (gr1 < n_nodes) t[gr1 * H1 + f] = (unsigned short)f2bf_rne(acc1);
}

// ---------------- edge pass: g[r] += val * t[c];  colsum[c] += val --------
// 8 lanes per edge, one bf16 PAIR per lane. Per edge: 8 pk_add_bf16 atomics
// (was 16 fp32) + 1 colsum atomic. t table is bf16 (3.2MB) -> fits per-XCD
// L2, gathers become L2 hits. g write sector per edge: 32B (was 64B).
__global__ __launch_bounds__(256) void k_edge(const int* __restrict__ rows,
                                              const int* __restrict__ cols,
                                              const float* __restrict__ vals,
                                              const unsigned int* __restrict__ tb,
                                              unsigned int* __restrict__ g2,
                                              float* __restrict__ colsum,
                                              int E) {
    int tid = blockIdx.x * 256 + threadIdx.x;
    int e = tid >> 3;
    int f2 = tid & 7;              // feature pair index: features 2*f2, 2*f2+1
    if (e >= E) return;
    int r = rows[e];
    int c = cols[e];
    float v = vals[e];
    unsigned int tv = tb[c * 8 + f2];                 // 32B/edge, L2-resident
    unsigned int pk = pack_bf16(v * bf_lo(tv), v * bf_hi(tv));
    unsigned int* addr = g2 + (r * 8 + f2);
    asm volatile("global_atomic_pk_add_bf16 %0, %1, off"
                 :: "v"(addr), "v"(pk) : "memory");
    if (f2 == 0) atomicAdd(&colsum[c], v);
}

// ---------------- s[f] = sum_j colsum[j] * relu(g[j][f]) ----------------
// 8 lanes per node row; each lane unpacks one bf16 pair.
__global__ __launch_bounds__(256) void k_s(const unsigned int* __restrict__ g2,
                                           const float* __restrict__ colsum,
                                           float* __restrict__ s,
                                           int n_nodes) {
    const int f2 = threadIdx.x & 7;
    int grp  = (blockIdx.x * 256 + threadIdx.x) >> 3;
    int ngrp = (gridDim.x * 256) >> 3;
    float accl = 0.f, acch = 0.f;
    for (int j = grp; j < n_nodes; j += ngrp) {
        float cv = colsum[j];
        unsigned int gv = g2[j * 8 + f2];             // wave reads 256B contig
        accl = fmaf(cv, fmaxf(bf_lo(gv), 0.f), accl);
        acch = fmaf(cv, fmaxf(bf_hi(gv), 0.f), acch);
    }
    // reduce the 8 node-subgroups within the wave (lanes l, l^8, l^16, l^32)
    accl += __shfl_xor(accl, 8, 64);
    accl += __shfl_xor(accl, 16, 64);
    accl += __shfl_xor(accl, 32, 64);
    acch += __shfl_xor(acch, 8, 64);
    acch += __shfl_xor(acch, 16, 64);
    acch += __shfl_xor(acch, 32, 64);
    __shared__ float red[4][16];
    int lane = threadIdx.x & 63, wid = threadIdx.x >> 6;
    if (lane < 8) { red[wid][2 * lane] = accl; red[wid][2 * lane + 1] = acch; }
    __syncthreads();
    if (threadIdx.x < 16) {
        float v = red[0][threadIdx.x] + red[1][threadIdx.x] +
                  red[2][threadIdx.x] + red[3][threadIdx.x];
        atomicAdd(&s[threadIdx.x], v);
    }
}

// ---------------- out = sigmoid((s @ W2) @ w_out + b_out) ----------------
__global__ void k_out(const float* __restrict__ s, const float* __restrict__ W2,
                      const float* __restrict__ w_out,
                      const float* __restrict__ b_out,
                      float* __restrict__ out) {
    int f2 = threadIdx.x;   // 64 threads, 32 active
    float m = 0.f;
    if (f2 < H2) {
        float v = 0.f;
#pragma unroll
        for (int f1 = 0; f1 < H1; f1++) v = fmaf(s[f1], W2[f1 * H2 + f2], v);
        m = v * w_out[f2];
    }
    for (int off = 32; off; off >>= 1) m += __shfl_down(m, off, 64);
    if (f2 == 0) out[0] = 1.f / (1.f + expf(-(m + b_out[0])));
}

extern "C" void kernel_launch(void* const* d_in, const int* in_sizes, int n_in,
                              void* d_out, int out_size, void* d_ws, size_t ws_size,
                              hipStream_t stream) {
    const float* x         = (const float*)d_in[0];
    const float* edge_vals = (const float*)d_in[1];
    const float* W1        = (const float*)d_in[2];
    const float* W2        = (const float*)d_in[3];
    const float* w_out     = (const float*)d_in[4];
    const float* b_out     = (const float*)d_in[5];
    const int*   edge_rows = (const int*)d_in[6];
    const int*   edge_cols = (const int*)d_in[7];
    float* out = (float*)d_out;

    const int N = N_NODES;
    const int E = in_sizes[1];   // 3.2M

    // workspace layout (bytes):
    //   t  (bf16): [0,         3,200,000)   N*16 bf16
    //   g  (bf16): [3,200,000, 6,400,000)   N*16 bf16  (zeroed)
    //   colsum:    [6,400,000, 6,800,000)   N fp32     (zeroed)
    //   s:         [6,800,000, 6,800,064)   16 fp32    (zeroed)
    char* ws = (char*)d_ws;
    unsigned short* t   = (unsigned short*)(ws);
    unsigned int*   g2  = (unsigned int*)(ws + 3200000);
    float* colsum = (float*)(ws + 6400000);
    float* s      = (float*)(ws + 6800000);

    // zero g + colsum + s: 3,600,064 B = 225,004 float4
    const int n4 = 225004;
    k_zero<<<(n4 + 255) / 256, 256, 0, stream>>>((float4*)(ws + 3200000), n4);

    k_xw1<<<(N + ROWS - 1) / ROWS, 256, 0, stream>>>(x, W1, t, N);

    long long edge_threads = (long long)E * 8;
    k_edge<<<(int)((edge_threads + 255) / 256), 256, 0, stream>>>(
        edge_rows, edge_cols, edge_vals, (const unsigned int*)t, g2, colsum, E);

    k_s<<<1024, 256, 0, stream>>>(g2, colsum, s, N);

    k_out<<<1, 64, 0, stream>>>(s, W2, w_out, b_out, out);
}

// Round 2
// 405.252 us; speedup vs baseline: 1.3286x; 1.3286x over previous
//
#include <hip/hip_runtime.h>
#include <math.h>

#define N_NODES 100000
#define D_IN 256
#define H1 16
#define H2 32

// ---------- bf16 helpers (manual, RNE) ----------
static __device__ __forceinline__ float bf_lo(unsigned int u) {
    return __uint_as_float(u << 16);
}
static __device__ __forceinline__ float bf_hi(unsigned int u) {
    return __uint_as_float(u & 0xffff0000u);
}
static __device__ __forceinline__ unsigned int f2bf_rne(float f) {
    unsigned int u = __float_as_uint(f);
    return (u + 0x7fffu + ((u >> 16) & 1u)) >> 16;
}
static __device__ __forceinline__ unsigned int pack_bf16(float lo, float hi) {
    return f2bf_rne(lo) | (f2bf_rne(hi) << 16);
}
// HW packed convert (RNE), no builtin on gfx950 -> inline asm (learn_hip m240)
static __device__ __forceinline__ unsigned int cvt_pk_bf16(float lo, float hi) {
    unsigned int r;
    asm("v_cvt_pk_bf16_f32 %0, %1, %2" : "=v"(r) : "v"(lo), "v"(hi));
    return r;
}

typedef __attribute__((ext_vector_type(8))) short bf16x8;   // MFMA A/B frag (4 VGPR)
typedef __attribute__((ext_vector_type(4))) float f32x4;    // MFMA C/D frag
union ABFrag { unsigned int u[4]; bf16x8 v; };

// ---------------- zero workspace region ----------------
__global__ void k_zero(float4* __restrict__ p, int n4) {
    int i = blockIdx.x * blockDim.x + threadIdx.x;
    if (i < n4) p[i] = make_float4(0.f, 0.f, 0.f, 0.f);
}

// ---------------- t = bf16(x @ W1) via MFMA 16x16x32 bf16 ----------------
// Per wave: B-frags (W1, 256x16) built once into 32 VGPRs, then 2 row-tiles
// of 16 rows each: 8 k-steps of {2x b128 x-load -> 4x v_cvt_pk_bf16 -> mfma}.
// Layouts (m89-verified family): A: row=l&15, k=(l>>4)*8+e;
// B: col=l&15, k=(l>>4)*8+e; D: col=l&15, row=(l>>4)*4+reg.
#define XW1_TILES 2   // row-tiles per wave
#define XW1_ROWS (4 * XW1_TILES * 16)   // rows per 256-thread block = 128
__global__ __launch_bounds__(256) void k_xw1(const float* __restrict__ x,
                                             const float* __restrict__ W1,
                                             unsigned short* __restrict__ t,
                                             int n_nodes) {
    const int lane = threadIdx.x & 63;
    const int wid  = threadIdx.x >> 6;
    const int fcol = lane & 15;   // A-row / B-col / D-col selector
    const int kgrp = lane >> 4;   // k-group 0..3 (8 consecutive k each)

    // B-frags: bfrag[g] covers W1[32g .. 32g+31][0..15]
    ABFrag bfrag[8];
#pragma unroll
    for (int g = 0; g < 8; g++) {
        const float* wp = W1 + (g * 32 + kgrp * 8) * H1 + fcol;
#pragma unroll
        for (int p = 0; p < 4; p++)
            bfrag[g].u[p] = cvt_pk_bf16(wp[(2 * p) * H1], wp[(2 * p + 1) * H1]);
    }

    const int wrow0 = blockIdx.x * XW1_ROWS + wid * (XW1_TILES * 16);
#pragma unroll
    for (int tile = 0; tile < XW1_TILES; tile++) {
        const int row0 = wrow0 + tile * 16;
        int arow = row0 + fcol;
        if (arow >= n_nodes) arow = n_nodes - 1;   // clamp for safe loads
        const float* xr = x + (size_t)arow * D_IN;
        f32x4 acc = {0.f, 0.f, 0.f, 0.f};
#pragma unroll
        for (int g = 0; g < 8; g++) {
            const float4 a0 = *(const float4*)(xr + g * 32 + kgrp * 8);
            const float4 a1 = *(const float4*)(xr + g * 32 + kgrp * 8 + 4);
            ABFrag af;
            af.u[0] = cvt_pk_bf16(a0.x, a0.y);
            af.u[1] = cvt_pk_bf16(a0.z, a0.w);
            af.u[2] = cvt_pk_bf16(a1.x, a1.y);
            af.u[3] = cvt_pk_bf16(a1.z, a1.w);
            acc = __builtin_amdgcn_mfma_f32_16x16x32_bf16(af.v, bfrag[g].v, acc, 0, 0, 0);
        }
#pragma unroll
        for (int r = 0; r < 4; r++) {
            int orow = row0 + kgrp * 4 + r;
            if (orow < n_nodes)
                t[(size_t)orow * H1 + fcol] = (unsigned short)f2bf_rne(acc[r]);
        }
    }
}

// ---------------- edge pass: g[r] += val * t[c]  (NO colsum) --------------
// 8 lanes per edge, one bf16 pair per lane -> exactly ONE random atomic
// line-transaction per edge (the measured 20G trans/s fabric ceiling).
__global__ __launch_bounds__(256) void k_edge(const int* __restrict__ rows,
                                              const int* __restrict__ cols,
                                              const float* __restrict__ vals,
                                              const unsigned int* __restrict__ tb,
                                              unsigned int* __restrict__ g2,
                                              int E) {
    int tid = blockIdx.x * 256 + threadIdx.x;
    int e = tid >> 3;
    int f2 = tid & 7;              // feature pair index
    if (e >= E) return;
    int r = rows[e];
    int c = cols[e];
    float v = vals[e];
    unsigned int tv = tb[c * 8 + f2];
    unsigned int pk = pack_bf16(v * bf_lo(tv), v * bf_hi(tv));
    unsigned int* addr = g2 + (r * 8 + f2);
    asm volatile("global_atomic_pk_add_bf16 %0, %1, off"
                 :: "v"(addr), "v"(pk) : "memory");
}

// ---------------- s[f] = sum_e val[e] * relu(g[col[e]])[f] ----------------
// colsum is never materialized: substitute its definition into the s-sum.
// Gathers of g are regular loads on a 3.2MB L2-resident table (not on the
// atomic path). 8 lanes per edge.
__global__ __launch_bounds__(256) void k_s2(const int* __restrict__ cols,
                                            const float* __restrict__ vals,
                                            const unsigned int* __restrict__ g2,
                                            float* __restrict__ s,
                                            int E) {
    const int f2 = threadIdx.x & 7;
    int idx    = (blockIdx.x * 256 + threadIdx.x) >> 3;
    int stride = (gridDim.x * 256) >> 3;
    float accl = 0.f, acch = 0.f;
    for (int e = idx; e < E; e += stride) {
        int c = cols[e];
        float v = vals[e];
        unsigned int gv = g2[c * 8 + f2];
        accl = fmaf(v, fmaxf(bf_lo(gv), 0.f), accl);
        acch = fmaf(v, fmaxf(bf_hi(gv), 0.f), acch);
    }
    // combine the 8 edge-subgroups in the wave (lanes l, l^8, l^16, l^32)
    accl += __shfl_xor(accl, 8, 64);
    accl += __shfl_xor(accl, 16, 64);
    accl += __shfl_xor(accl, 32, 64);
    acch += __shfl_xor(acch, 8, 64);
    acch += __shfl_xor(acch, 16, 64);
    acch += __shfl_xor(acch, 32, 64);
    __shared__ float red[4][16];
    int lane = threadIdx.x & 63, wid = threadIdx.x >> 6;
    if (lane < 8) { red[wid][2 * lane] = accl; red[wid][2 * lane + 1] = acch; }
    __syncthreads();
    if (threadIdx.x < 16) {
        float v = red[0][threadIdx.x] + red[1][threadIdx.x] +
                  red[2][threadIdx.x] + red[3][threadIdx.x];
        atomicAdd(&s[threadIdx.x], v);
    }
}

// ---------------- out = sigmoid((s @ W2) @ w_out + b_out) ----------------
__global__ void k_out(const float* __restrict__ s, const float* __restrict__ W2,
                      const float* __restrict__ w_out,
                      const float* __restrict__ b_out,
                      float* __restrict__ out) {
    int f2 = threadIdx.x;   // 64 threads, 32 active
    float m = 0.f;
    if (f2 < H2) {
        float v = 0.f;
#pragma unroll
        for (int f1 = 0; f1 < H1; f1++) v = fmaf(s[f1], W2[f1 * H2 + f2], v);
        m = v * w_out[f2];
    }
    for (int off = 32; off; off >>= 1) m += __shfl_down(m, off, 64);
    if (f2 == 0) out[0] = 1.f / (1.f + expf(-(m + b_out[0])));
}

extern "C" void kernel_launch(void* const* d_in, const int* in_sizes, int n_in,
                              void* d_out, int out_size, void* d_ws, size_t ws_size,
                              hipStream_t stream) {
    const float* x         = (const float*)d_in[0];
    const float* edge_vals = (const float*)d_in[1];
    const float* W1        = (const float*)d_in[2];
    const float* W2        = (const float*)d_in[3];
    const float* w_out     = (const float*)d_in[4];
    const float* b_out     = (const float*)d_in[5];
    const int*   edge_rows = (const int*)d_in[6];
    const int*   edge_cols = (const int*)d_in[7];
    float* out = (float*)d_out;

    const int N = N_NODES;
    const int E = in_sizes[1];   // 3.2M

    // workspace layout (bytes):
    //   g  (bf16): [0,         3,200,000)   N*16 bf16  (zeroed)
    //   s:         [3,200,000, 3,200,064)   16 fp32    (zeroed)
    //   t  (bf16): [3,200,064, 6,400,064)   N*16 bf16
    char* ws = (char*)d_ws;
    unsigned int*   g2 = (unsigned int*)(ws);
    float*          s  = (float*)(ws + 3200000);
    unsigned short* t  = (unsigned short*)(ws + 3200064);

    // zero g + s: 3,200,064 B = 200,004 float4
    const int n4 = 200004;
    k_zero<<<(n4 + 255) / 256, 256, 0, stream>>>((float4*)ws, n4);

    k_xw1<<<(N + XW1_ROWS - 1) / XW1_ROWS, 256, 0, stream>>>(x, W1, t, N);

    long long edge_threads = (long long)E * 8;
    k_edge<<<(int)((edge_threads + 255) / 256), 256, 0, stream>>>(
        edge_rows, edge_cols, edge_vals, (const unsigned int*)t, g2, E);

    k_s2<<<1024, 256, 0, stream>>>(edge_cols, edge_vals, g2, s, E);

    k_out<<<1, 64, 0, stream>>>(s, W2, w_out, b_out, out);
}